// Round 9
// baseline (80.197 us; speedup 1.0000x reference)
//
#include <hip/hip_runtime.h>
#include <stdint.h>
#include <math.h>

typedef short v8s __attribute__((ext_vector_type(8)));
typedef float v4f __attribute__((ext_vector_type(4)));

#define DEVI static __device__ __forceinline__
#define AS1 __attribute__((address_space(1)))
#define AS3 __attribute__((address_space(3)))

static constexpr int Bn = 2;
static constexpr int Tn = 2048;
static constexpr int Hn = 16;
static constexpr int Gn = 4;
static constexpr int NQKV = 1536;   // H*D + 2*G*D
static constexpr int WIN = 512;
static constexpr int SINKN = 4;
#define SCALE_L2E (0.125f * 1.4426950408889634f)   // D^-0.5 * log2(e), folded into Wq/bq

DEVI unsigned short f2bf(float f) {
  unsigned u = __float_as_uint(f);
  u += 0x7fffu + ((u >> 16) & 1u);
  return (unsigned short)(u >> 16);
}
DEVI float bf2f(unsigned short h) { return __uint_as_float(((unsigned)h) << 16); }
// pack two f32 -> bf16x2 by truncation: low short = lo, high short = hi
DEVI unsigned pack_bf2(float hi, float lo) {
  return __builtin_amdgcn_perm(__float_as_uint(hi), __float_as_uint(lo), 0x07060302u);
}

// ------------- weights transpose + rope table + bias + x-convert, one launch -------------
// z: 0=Wq(scale) 1=Wk 2=Wv 3=Wo 4=rope-table+bias-concat 5=x fp32->bf16
__global__ __launch_bounds__(256) void k_transpose_all(const float* __restrict__ Wq,
                                                       const float* __restrict__ Wk,
                                                       const float* __restrict__ Wv,
                                                       const float* __restrict__ Wo,
                                                       unsigned short* __restrict__ wt_qkv,
                                                       unsigned short* __restrict__ wt_o,
                                                       const int* __restrict__ posp,
                                                       float2* __restrict__ table,
                                                       const float* __restrict__ bq,
                                                       const float* __restrict__ bk,
                                                       const float* __restrict__ bv,
                                                       float* __restrict__ biasout,
                                                       const float* __restrict__ x,
                                                       unsigned short* __restrict__ xb) {
  int z = blockIdx.z;
  int tx = threadIdx.x, ty = threadIdx.y;   // block (32,8)
  if (z == 5) {
    // x -> bf16, 4 float4 per thread (1024 blocks * 256 thr * 4 = 1,048,576 float4)
    int base = (blockIdx.y * 32 + blockIdx.x) * 256 + ty * 32 + tx;
    #pragma unroll
    for (int j = 0; j < 4; ++j) {
      int i = base + j * 262144;
      float4 v = ((const float4*)x)[i];
      ushort4 o;
      o.x = f2bf(v.x); o.y = f2bf(v.y); o.z = f2bf(v.z); o.w = f2bf(v.w);
      ((ushort4*)xb)[i] = o;
    }
    return;
  }
  if (z == 4) {
    int i = (blockIdx.y * 32 + blockIdx.x) * 256 + ty * 32 + tx;
    if (i < Tn * 32) {
      int t = i >> 5, d2 = i & 31;
      float inv = powf(10000.f, -(float)d2 / 32.f);
      float theta = (float)(posp[0] + t) * inv;
      float s, c;
      sincosf(theta, &s, &c);
      table[i] = make_float2(c, s);
    }
    if (i < NQKV)
      biasout[i] = (i < 1024) ? bq[i] * SCALE_L2E : (i < 1280 ? bk[i - 1024] : bv[i - 1280]);
    return;
  }
  const float* W; unsigned short* Wt; int N; float scale = 1.f;
  if (z == 0)      { W = Wq; Wt = wt_qkv;                 N = 1024; scale = SCALE_L2E; }
  else if (z == 1) { W = Wk; Wt = wt_qkv + 1024 * 1024;   N = 256; }
  else if (z == 2) { W = Wv; Wt = wt_qkv + 1280 * 1024;   N = 256; }
  else             { W = Wo; Wt = wt_o;                   N = 1024; }
  int n0 = blockIdx.x * 32, k0 = blockIdx.y * 32;
  if (n0 >= N) return;
  __shared__ float tile[32][33];
  #pragma unroll
  for (int yy = 0; yy < 4; ++yy)
    tile[ty + yy * 8][tx] = W[(size_t)(k0 + ty + yy * 8) * N + n0 + tx];
  __syncthreads();
  #pragma unroll
  for (int yy = 0; yy < 4; ++yy)
    Wt[(size_t)(n0 + ty + yy * 8) * 1024 + k0 + tx] = f2bf(tile[tx][ty + yy * 8] * scale);
}

// ---------------- GEMM1: qkv = x @ [Wq|Wk|Wv]^T + bias, RoPE + vt epilogues ----------------
// 64x128 tile, BK=128, 4 waves (2 wm x 2 wn), single-buffer 2-barrier per 128-wide K-step.
// LDS 48KB -> exactly 3 blocks/CU (matches 768-block grid). XOR-swizzled chunks (T2/rule21).
__global__ __launch_bounds__(256) void k_gemm_qkv(const unsigned short* __restrict__ A,
                                                  const unsigned short* __restrict__ Bt,
                                                  const float* __restrict__ bias,
                                                  const float2* __restrict__ table,
                                                  unsigned short* __restrict__ outH,
                                                  unsigned short* __restrict__ vtH,
                                                  int M, int N, int K) {
  __shared__ char As[16384];    // [64 rows][256 B] (128 bf16)
  __shared__ char Bs[32768];    // [128 rows][256 B]
  int nx = gridDim.x;
  int nwg = nx * gridDim.y;
  int id = blockIdx.y * nx + blockIdx.x;
  int swz = (id & 7) * (nwg >> 3) + (id >> 3);
  int m0 = (swz / nx) * 64, n0 = (swz % nx) * 128;

  int t = threadIdx.x, lane = t & 63, wave = t >> 6;
  int wm = wave >> 1, wn = wave & 1;
  int l15 = lane & 15, l4 = lane >> 4;
  int l7 = l15 & 7;
  v4f acc[2][4] = {};

  for (int k0 = 0; k0 < K; k0 += 128) {
    __syncthreads();
    #pragma unroll
    for (int p = 0; p < 4; ++p) {     // A: 64 rows x 16 chunks = 1024 chunks of 16B
      int cid = p * 256 + t;
      int row = cid >> 4, cc = cid & 15;
      const unsigned short* ga = A + (size_t)(m0 + row) * K + k0 + (cc ^ (row & 7)) * 8;
      __builtin_amdgcn_global_load_lds((const AS1 void*)ga,
                                       (AS3 void*)(As + p * 4096 + wave * 1024), 16, 0, 0);
    }
    #pragma unroll
    for (int p = 0; p < 8; ++p) {     // B: 128 rows x 16 chunks = 2048 chunks of 16B
      int cid = p * 256 + t;
      int row = cid >> 4, cc = cid & 15;
      const unsigned short* gb = Bt + (size_t)(n0 + row) * K + k0 + (cc ^ (row & 7)) * 8;
      __builtin_amdgcn_global_load_lds((const AS1 void*)gb,
                                       (AS3 void*)(Bs + p * 4096 + wave * 1024), 16, 0, 0);
    }
    __syncthreads();
    #pragma unroll
    for (int kk = 0; kk < 4; ++kk) {
      v8s af[2], bfr[4];
      #pragma unroll
      for (int mi = 0; mi < 2; ++mi)
        af[mi] = *(const v8s*)(As + (wm * 32 + mi * 16 + l15) * 256 + (((kk * 4 + l4) ^ l7) << 4));
      #pragma unroll
      for (int ni = 0; ni < 4; ++ni)
        bfr[ni] = *(const v8s*)(Bs + (wn * 64 + ni * 16 + l15) * 256 + (((kk * 4 + l4) ^ l7) << 4));
      #pragma unroll
      for (int mi = 0; mi < 2; ++mi)
        #pragma unroll
        for (int ni = 0; ni < 4; ++ni)
          acc[mi][ni] = __builtin_amdgcn_mfma_f32_16x16x32_bf16(af[mi], bfr[ni], acc[mi][ni], 0, 0, 0);
    }
  }

  if (n0 >= 1280) {
    // v columns -> Vt[b][g][d][t], 4 contiguous t per lane
    #pragma unroll
    for (int mi = 0; mi < 2; ++mi) {
      #pragma unroll
      for (int ni = 0; ni < 4; ++ni) {
        int col = n0 + wn * 64 + ni * 16 + l15;
        float bv = bias[col];
        int c2 = col - 1280;
        int gg = c2 >> 6, dd = c2 & 63;
        int row = m0 + wm * 32 + mi * 16 + l4 * 4;
        int bb = row >> 11, tt = row & 2047;
        ushort4 ov;
        ov.x = f2bf(acc[mi][ni][0] + bv);
        ov.y = f2bf(acc[mi][ni][1] + bv);
        ov.z = f2bf(acc[mi][ni][2] + bv);
        ov.w = f2bf(acc[mi][ni][3] + bv);
        *(ushort4*)(vtH + ((size_t)((bb * Gn + gg) * 64 + dd)) * Tn + tt) = ov;
      }
    }
  } else {
    // q/k region: fused interleaved RoPE. col parity == lane parity, partner = lane^1.
    #pragma unroll
    for (int mi = 0; mi < 2; ++mi) {
      #pragma unroll
      for (int ni = 0; ni < 4; ++ni) {
        int col = n0 + wn * 64 + ni * 16 + l15;
        float bv = bias[col];
        int d2 = (col & 63) >> 1;
        bool even = !(col & 1);
        #pragma unroll
        for (int r = 0; r < 4; ++r) {
          int row = m0 + wm * 32 + mi * 16 + l4 * 4 + r;
          int tt = row & 2047;
          float2 cs = table[tt * 32 + d2];
          float v = acc[mi][ni][r] + bv;
          float prt = __shfl_xor(v, 1);
          float ov = even ? (v * cs.x - prt * cs.y) : (prt * cs.y + v * cs.x);
          outH[(size_t)row * N + col] = f2bf(ov);
        }
      }
    }
  }
}

// ---------------- GEMM2: out = attn @ Wo^T + bo (f32) ----------------
// 128x128 tile, BK=64, 8 waves (2 wm x 4 wn, wave tile 64x32), 256 blocks = 1/CU balanced.
__global__ __launch_bounds__(512) void k_gemm_o(const unsigned short* __restrict__ A,
                                                const unsigned short* __restrict__ Bt,
                                                const float* __restrict__ bias,
                                                float* __restrict__ outF,
                                                int M, int N, int K) {
  __shared__ char As[16384];    // [128 rows][128 B]
  __shared__ char Bs[16384];    // [128 rows][128 B]
  int nx = gridDim.x;
  int nwg = nx * gridDim.y;
  int id = blockIdx.y * nx + blockIdx.x;
  int swz = (id & 7) * (nwg >> 3) + (id >> 3);
  int m0 = (swz / nx) * 128, n0 = (swz % nx) * 128;

  int t = threadIdx.x, lane = t & 63, wave = t >> 6;
  int wm = wave >> 2, wn = wave & 3;
  int l15 = lane & 15, l4 = lane >> 4;
  int l7 = l15 & 7;
  v4f acc[4][2] = {};

  for (int k0 = 0; k0 < K; k0 += 64) {
    __syncthreads();
    #pragma unroll
    for (int p = 0; p < 2; ++p) {     // A: 128 rows x 8 chunks = 1024 chunks of 16B
      int cid = p * 512 + t;
      int row = cid >> 3, cc = cid & 7;
      const unsigned short* ga = A + (size_t)(m0 + row) * K + k0 + (cc ^ (row & 7)) * 8;
      __builtin_amdgcn_global_load_lds((const AS1 void*)ga,
                                       (AS3 void*)(As + p * 8192 + wave * 1024), 16, 0, 0);
    }
    #pragma unroll
    for (int p = 0; p < 2; ++p) {     // B: 1024 chunks of 16B
      int cid = p * 512 + t;
      int row = cid >> 3, cc = cid & 7;
      const unsigned short* gb = Bt + (size_t)(n0 + row) * K + k0 + (cc ^ (row & 7)) * 8;
      __builtin_amdgcn_global_load_lds((const AS1 void*)gb,
                                       (AS3 void*)(Bs + p * 8192 + wave * 1024), 16, 0, 0);
    }
    __syncthreads();
    #pragma unroll
    for (int kk = 0; kk < 2; ++kk) {
      v8s af[4], bfr[2];
      #pragma unroll
      for (int mi = 0; mi < 4; ++mi)
        af[mi] = *(const v8s*)(As + (wm * 64 + mi * 16 + l15) * 128 + (((kk * 4 + l4) ^ l7) << 4));
      #pragma unroll
      for (int ni = 0; ni < 2; ++ni)
        bfr[ni] = *(const v8s*)(Bs + (wn * 32 + ni * 16 + l15) * 128 + (((kk * 4 + l4) ^ l7) << 4));
      #pragma unroll
      for (int mi = 0; mi < 4; ++mi)
        #pragma unroll
        for (int ni = 0; ni < 2; ++ni)
          acc[mi][ni] = __builtin_amdgcn_mfma_f32_16x16x32_bf16(af[mi], bfr[ni], acc[mi][ni], 0, 0, 0);
    }
  }

  #pragma unroll
  for (int mi = 0; mi < 4; ++mi) {
    #pragma unroll
    for (int ni = 0; ni < 2; ++ni) {
      int col = n0 + wn * 32 + ni * 16 + l15;
      float bv = bias[col];
      #pragma unroll
      for (int r = 0; r < 4; ++r) {
        int row = m0 + wm * 64 + mi * 16 + l4 * 4 + r;
        outF[(size_t)row * N + col] = acc[mi][ni][r] + bv;
      }
    }
  }
}

// ---------------- Flash attention, GQA + sliding window + sink (R8 structure) ----------------
__global__ __launch_bounds__(512) void k_attn(const unsigned short* __restrict__ qkv,
                                              const unsigned short* __restrict__ vt,
                                              unsigned short* __restrict__ o) {
  __shared__ char smem[2 * 16384 + 16384];    // 2 bufs (K 8KB | V^T 8KB) + 8 waves x 2KB P
  int id = blockIdx.x;
  int half = id >> 8, r5 = id & 255;
  int h = r5 >> 4;
  int qtile = half ? (15 - (r5 & 15)) : (r5 & 15);
  int b = half;
  int qt0 = qtile * 128;
  int g = h >> 2;
  int t = threadIdx.x, lane = t & 63, wave = t >> 6;
  int l15 = lane & 15, l4 = lane >> 4;
  int l7 = l15 & 7;
  int qw0 = qt0 + wave * 16;
  char* Pb = smem + 32768 + wave * 2048;

  int jt_end = (qt0 + 127) >> 6;
  int wstart = (qt0 > WIN) ? ((qt0 - WIN) >> 6) : 0;
  int nIt = jt_end - wstart + 1;
  bool sinkPre = (wstart > 0);

  const unsigned short* gk0 = qkv + (size_t)(b * Tn) * NQKV + 1024 + g * 64;
  const unsigned short* gv0 = vt + (size_t)((b * Gn + g) * 64) * Tn;

  int sr = t >> 3, sc = t & 7;
  int scs = (sc ^ (sr & 7)) << 3;
  const unsigned short* gkb = gk0 + (size_t)sr * NQKV + scs;
  const unsigned short* gvb = gv0 + (size_t)sr * Tn + scs;

  auto stageKV = [&](int buf, int j0) {
    __builtin_amdgcn_global_load_lds((const AS1 void*)(gkb + (size_t)j0 * NQKV),
                                     (AS3 void*)(smem + buf * 16384 + wave * 1024), 16, 0, 0);
    __builtin_amdgcn_global_load_lds((const AS1 void*)(gvb + j0),
                                     (AS3 void*)(smem + buf * 16384 + 8192 + wave * 1024), 16, 0, 0);
  };

  stageKV(0, wstart << 6);

  v8s Qf[2];
  #pragma unroll
  for (int hf = 0; hf < 2; ++hf)
    Qf[hf] = *(const v8s*)(qkv + (size_t)(b * Tn + qw0 + l15) * NQKV + h * 64 + hf * 32 + l4 * 8);

  float m = -INFINITY, lsm = 0.f;   // lsm per-lane partial; reduced at end
  v4f accO[4] = {};

  if (sinkPre) {
    const unsigned short* kr = gk0 + (size_t)l15 * NQKV + l4 * 8;
    v8s kf0 = *(const v8s*)(kr);
    v8s kf1 = *(const v8s*)(kr + 32);
    v4f z = {};
    z = __builtin_amdgcn_mfma_f32_16x16x32_bf16(kf0, Qf[0], z, 0, 0, 0);
    z = __builtin_amdgcn_mfma_f32_16x16x32_bf16(kf1, Qf[1], z, 0, 0, 0);
    float mt = -1e30f;
    float pv4[4];
    #pragma unroll
    for (int r = 0; r < 4; ++r) {
      float sv = (l4 == 0) ? z[r] : -1e30f;
      pv4[r] = sv;
      mt = fmaxf(mt, sv);
    }
    mt = fmaxf(mt, __shfl_xor(mt, 16));
    mt = fmaxf(mt, __shfl_xor(mt, 32));
    m = mt;
    float p0 = exp2f(pv4[0] - m), p1 = exp2f(pv4[1] - m);
    float p2 = exp2f(pv4[2] - m), p3 = exp2f(pv4[3] - m);
    lsm = (p0 + p1) + (p2 + p3);
    unsigned long long w = ((unsigned long long)pack_bf2(p3, p2) << 32) | pack_bf2(p1, p0);
    *(unsigned long long*)(Pb + l15 * 128 + ((l4 * 8) ^ (l7 << 4))) = w;
    *(unsigned long long*)(Pb + l15 * 128 + ((32 + l4 * 8) ^ (l7 << 4))) = 0ull;
    asm volatile("s_waitcnt lgkmcnt(0)" ::: "memory");
    __builtin_amdgcn_sched_barrier(0);
    v8s pfrag = *(const v8s*)(Pb + l15 * 128 + ((l4 * 16) ^ (l7 << 4)));
    #pragma unroll
    for (int db = 0; db < 4; ++db) {
      int d = db * 16 + l15;
      v8s vf = *(const v8s*)(gv0 + (size_t)d * Tn + l4 * 8);
      accO[db] = __builtin_amdgcn_mfma_f32_16x16x32_bf16(vf, pfrag, accO[db], 0, 0, 0);
    }
  }

  __syncthreads();

  for (int it = 0; it < nIt; ++it) {
    int cur = it & 1;
    if (it + 1 < nIt) stageKV(cur ^ 1, (wstart + it + 1) << 6);
    int j0 = (wstart + it) << 6;

    bool skip = (j0 > qw0 + 15) || ((j0 + 63 < qw0 - WIN) && (j0 >= SINKN));
    if (!skip) {
      const char* Kb = smem + cur * 16384;
      const char* Vb = Kb + 8192;
      v4f s[4];
      __builtin_amdgcn_s_setprio(1);
      #pragma unroll
      for (int kb = 0; kb < 4; ++kb) {
        int r = kb * 16 + l15;
        v8s kf0 = *(const v8s*)(Kb + r * 128 + ((l4 ^ (r & 7)) << 4));
        v8s kf1 = *(const v8s*)(Kb + r * 128 + (((4 + l4) ^ (r & 7)) << 4));
        v4f z = {};
        z = __builtin_amdgcn_mfma_f32_16x16x32_bf16(kf0, Qf[0], z, 0, 0, 0);
        s[kb] = __builtin_amdgcn_mfma_f32_16x16x32_bf16(kf1, Qf[1], z, 0, 0, 0);
      }
      __builtin_amdgcn_s_setprio(0);
      bool needMask = !((j0 + 63 <= qw0) && (j0 >= qw0 + 15 - WIN));
      if (needMask) {
        #pragma unroll
        for (int kb = 0; kb < 4; ++kb)
          #pragma unroll
          for (int r = 0; r < 4; ++r) {
            int j = j0 + kb * 16 + l4 * 4 + r;
            int qg = qw0 + l15;
            bool valid = (j <= qg) && ((j >= qg - WIN) || (j < SINKN));
            s[kb][r] = valid ? s[kb][r] : -1e30f;
          }
      }
      float mt = -1e30f;
      #pragma unroll
      for (int kb = 0; kb < 4; ++kb)
        #pragma unroll
        for (int r = 0; r < 4; ++r) mt = fmaxf(mt, s[kb][r]);
      mt = fmaxf(mt, __shfl_xor(mt, 16));
      mt = fmaxf(mt, __shfl_xor(mt, 32));
      if (!__all(mt <= m + 8.f)) {      // T13 defer-max
        float mnew = fmaxf(m, mt);
        float alpha = exp2f(m - mnew);
        lsm *= alpha;
        #pragma unroll
        for (int db = 0; db < 4; ++db) {
          accO[db][0] *= alpha; accO[db][1] *= alpha;
          accO[db][2] *= alpha; accO[db][3] *= alpha;
        }
        m = mnew;
      }
      float lsum = 0.f;
      #pragma unroll
      for (int kb = 0; kb < 4; ++kb) {
        float p0 = exp2f(s[kb][0] - m);
        float p1 = exp2f(s[kb][1] - m);
        float p2 = exp2f(s[kb][2] - m);
        float p3 = exp2f(s[kb][3] - m);
        lsum += (p0 + p1) + (p2 + p3);
        unsigned lo = pack_bf2(p1, p0);
        unsigned hi = pack_bf2(p3, p2);
        unsigned long long w = ((unsigned long long)hi << 32) | lo;
        *(unsigned long long*)(Pb + l15 * 128 + ((kb * 32 + l4 * 8) ^ (l7 << 4))) = w;
      }
      lsm += lsum;
      asm volatile("s_waitcnt lgkmcnt(0)" ::: "memory");
      __builtin_amdgcn_sched_barrier(0);

      __builtin_amdgcn_s_setprio(1);
      #pragma unroll
      for (int kc = 0; kc < 2; ++kc) {
        v8s pfrag = *(const v8s*)(Pb + l15 * 128 + ((kc * 64 + l4 * 16) ^ (l7 << 4)));
        #pragma unroll
        for (int db = 0; db < 4; ++db) {
          int d = db * 16 + l15;
          v8s vf = *(const v8s*)(Vb + d * 128 + (((kc * 4 + l4) ^ (d & 7)) << 4));
          accO[db] = __builtin_amdgcn_mfma_f32_16x16x32_bf16(vf, pfrag, accO[db], 0, 0, 0);
        }
      }
      __builtin_amdgcn_s_setprio(0);
    }
    __syncthreads();
  }

  lsm += __shfl_xor(lsm, 16);
  lsm += __shfl_xor(lsm, 32);
  float inv = 1.f / lsm;
  size_t orow = (size_t)(b * Tn + qw0 + l15) * 1024 + h * 64;
  #pragma unroll
  for (int db = 0; db < 4; ++db) {
    int d0 = db * 16 + l4 * 4;
    ushort4 ov;
    ov.x = f2bf(accO[db][0] * inv);
    ov.y = f2bf(accO[db][1] * inv);
    ov.z = f2bf(accO[db][2] * inv);
    ov.w = f2bf(accO[db][3] * inv);
    *(ushort4*)(o + orow + d0) = ov;
  }
}

extern "C" void kernel_launch(void* const* d_in, const int* in_sizes, int n_in,
                              void* d_out, int out_size, void* d_ws, size_t ws_size,
                              hipStream_t stream) {
  const float* x  = (const float*)d_in[0];
  const float* Wq = (const float*)d_in[1];
  const float* bq = (const float*)d_in[2];
  const float* Wk = (const float*)d_in[3];
  const float* bk = (const float*)d_in[4];
  const float* Wv = (const float*)d_in[5];
  const float* bv = (const float*)d_in[6];
  const float* Wo = (const float*)d_in[7];
  const float* bo = (const float*)d_in[8];
  const int*   pos = (const int*)d_in[9];
  float* out = (float*)d_out;

  char* ws = (char*)d_ws;
  unsigned short* xb      = (unsigned short*)(ws);                        // 8388608 B (reused as attno)
  unsigned short* wt_qkv  = (unsigned short*)(ws + 8388608);              // 3145728 B
  unsigned short* wt_o    = (unsigned short*)(ws + 11534336);             // 2097152 B
  float*          bias_q  = (float*)(ws + 13631488);                      // 6144 B
  float2*         table   = (float2*)(ws + 13637632);                     // 524288 B
  unsigned short* qkvb    = (unsigned short*)(ws + 14161920);             // 12582912 B
  unsigned short* vt      = (unsigned short*)(ws + 26744832);             // 2097152 B
  unsigned short* attno   = xb;                                           // reuse (x bf16 dead after GEMM1)

  // weights transpose + rope table + bias + x convert, one launch
  k_transpose_all<<<dim3(32, 32, 6), dim3(32, 8), 0, stream>>>(Wq, Wk, Wv, Wo, wt_qkv, wt_o,
                                                               pos, table, bq, bk, bv, bias_q,
                                                               x, xb);
  // qkv = x @ [Wq|Wk|Wv] + bias; q,k -> RoPE'd bf16 in qkvb, v -> vt transposed
  k_gemm_qkv<<<dim3(12, 64), 256, 0, stream>>>(xb, wt_qkv, bias_q, table, qkvb, vt,
                                               4096, NQKV, 1024);
  // attention (load-balanced 1D grid)
  k_attn<<<512, 512, 0, stream>>>(qkvb, vt, attno);
  // out = attn @ Wo + bo  (f32 out)
  k_gemm_o<<<dim3(8, 32), 512, 0, stream>>>(attno, wt_o, bo, out, 4096, 1024, 1024);
}

// Round 10
// 78.559 us; speedup vs baseline: 1.0209x; 1.0209x over previous
//
#include <hip/hip_runtime.h>
#include <stdint.h>
#include <math.h>

typedef short v8s __attribute__((ext_vector_type(8)));
typedef float v4f __attribute__((ext_vector_type(4)));

#define DEVI static __device__ __forceinline__
#define AS1 __attribute__((address_space(1)))
#define AS3 __attribute__((address_space(3)))

static constexpr int Bn = 2;
static constexpr int Tn = 2048;
static constexpr int Hn = 16;
static constexpr int Gn = 4;
static constexpr int NQKV = 1536;   // H*D + 2*G*D
static constexpr int WIN = 512;
static constexpr int SINKN = 4;
#define SCALE_L2E (0.125f * 1.4426950408889634f)   // D^-0.5 * log2(e), folded into Wq/bq

DEVI unsigned short f2bf(float f) {
  unsigned u = __float_as_uint(f);
  u += 0x7fffu + ((u >> 16) & 1u);
  return (unsigned short)(u >> 16);
}
DEVI float bf2f(unsigned short h) { return __uint_as_float(((unsigned)h) << 16); }
// pack two f32 -> bf16x2 by truncation: low short = lo, high short = hi
DEVI unsigned pack_bf2(float hi, float lo) {
  return __builtin_amdgcn_perm(__float_as_uint(hi), __float_as_uint(lo), 0x07060302u);
}

// ------------- weights transpose + rope table + bias + x-convert, one launch -------------
// z: 0=Wq(scale) 1=Wk 2=Wv 3=Wo 4=rope-table+bias-concat 5=x fp32->bf16
__global__ __launch_bounds__(256) void k_transpose_all(const float* __restrict__ Wq,
                                                       const float* __restrict__ Wk,
                                                       const float* __restrict__ Wv,
                                                       const float* __restrict__ Wo,
                                                       unsigned short* __restrict__ wt_qkv,
                                                       unsigned short* __restrict__ wt_o,
                                                       const int* __restrict__ posp,
                                                       float2* __restrict__ table,
                                                       const float* __restrict__ bq,
                                                       const float* __restrict__ bk,
                                                       const float* __restrict__ bv,
                                                       float* __restrict__ biasout,
                                                       const float* __restrict__ x,
                                                       unsigned short* __restrict__ xb) {
  int z = blockIdx.z;
  int tx = threadIdx.x, ty = threadIdx.y;   // block (32,8)
  if (z == 5) {
    // x -> bf16, 4 float4 per thread (1024 blocks * 256 thr * 4 = 1,048,576 float4)
    int base = (blockIdx.y * 32 + blockIdx.x) * 256 + ty * 32 + tx;
    #pragma unroll
    for (int j = 0; j < 4; ++j) {
      int i = base + j * 262144;
      float4 v = ((const float4*)x)[i];
      ushort4 o;
      o.x = f2bf(v.x); o.y = f2bf(v.y); o.z = f2bf(v.z); o.w = f2bf(v.w);
      ((ushort4*)xb)[i] = o;
    }
    return;
  }
  if (z == 4) {
    int i = (blockIdx.y * 32 + blockIdx.x) * 256 + ty * 32 + tx;
    if (i < Tn * 32) {
      int t = i >> 5, d2 = i & 31;
      float inv = powf(10000.f, -(float)d2 / 32.f);
      float theta = (float)(posp[0] + t) * inv;
      float s, c;
      sincosf(theta, &s, &c);
      table[i] = make_float2(c, s);
    }
    if (i < NQKV)
      biasout[i] = (i < 1024) ? bq[i] * SCALE_L2E : (i < 1280 ? bk[i - 1024] : bv[i - 1280]);
    return;
  }
  const float* W; unsigned short* Wt; int N; float scale = 1.f;
  if (z == 0)      { W = Wq; Wt = wt_qkv;                 N = 1024; scale = SCALE_L2E; }
  else if (z == 1) { W = Wk; Wt = wt_qkv + 1024 * 1024;   N = 256; }
  else if (z == 2) { W = Wv; Wt = wt_qkv + 1280 * 1024;   N = 256; }
  else             { W = Wo; Wt = wt_o;                   N = 1024; }
  int n0 = blockIdx.x * 32, k0 = blockIdx.y * 32;
  if (n0 >= N) return;
  __shared__ float tile[32][33];
  #pragma unroll
  for (int yy = 0; yy < 4; ++yy)
    tile[ty + yy * 8][tx] = W[(size_t)(k0 + ty + yy * 8) * N + n0 + tx];
  __syncthreads();
  #pragma unroll
  for (int yy = 0; yy < 4; ++yy)
    Wt[(size_t)(n0 + ty + yy * 8) * 1024 + k0 + tx] = f2bf(tile[tx][ty + yy * 8] * scale);
}

// ---------------- GEMM: C[M][N] = A[M][K](bf16) * Bt[N][K]^T + bias ----------------
// 64x128 tile, BK=64, 4 waves (2 wm x 2 wn), single-buffer 2-barrier per K-step.
// LDS tiles XOR-swizzled (16B chunk ^= row&7) via pre-swizzled global source (T2/rule21).
// XCD-aware tile swizzle (nwg % 8 == 0 required).  [R8-proven config]
template <bool F32OUT>
__global__ __launch_bounds__(256) void k_gemm_bt(const unsigned short* __restrict__ A,
                                                 const unsigned short* __restrict__ Bt,
                                                 const float* __restrict__ bias,
                                                 const float2* __restrict__ table,
                                                 float* __restrict__ outF,
                                                 unsigned short* __restrict__ outH,
                                                 unsigned short* __restrict__ vtH,
                                                 int M, int N, int K) {
  __shared__ char As[8192];     // [64 rows][128 B] (64 bf16)
  __shared__ char Bs[16384];    // [128 rows][128 B]
  int nx = gridDim.x;
  int nwg = nx * gridDim.y;
  int id = blockIdx.y * nx + blockIdx.x;
  int swz = (id & 7) * (nwg >> 3) + (id >> 3);
  int m0 = (swz / nx) * 64, n0 = (swz % nx) * 128;

  int t = threadIdx.x, lane = t & 63, wave = t >> 6;
  int wm = wave >> 1, wn = wave & 1;
  int l15 = lane & 15, l4 = lane >> 4;
  int l7 = l15 & 7;
  v4f acc[2][4] = {};

  for (int k0 = 0; k0 < K; k0 += 64) {
    __syncthreads();
    #pragma unroll
    for (int p = 0; p < 2; ++p) {     // A: 512 chunks of 16B
      int cid = p * 256 + t;
      int row = cid >> 3, cc = cid & 7;
      const unsigned short* ga = A + (size_t)(m0 + row) * K + k0 + (cc ^ (row & 7)) * 8;
      __builtin_amdgcn_global_load_lds((const AS1 void*)ga,
                                       (AS3 void*)(As + p * 4096 + wave * 1024), 16, 0, 0);
    }
    #pragma unroll
    for (int p = 0; p < 4; ++p) {     // B: 1024 chunks of 16B
      int cid = p * 256 + t;
      int row = cid >> 3, cc = cid & 7;
      const unsigned short* gb = Bt + (size_t)(n0 + row) * K + k0 + (cc ^ (row & 7)) * 8;
      __builtin_amdgcn_global_load_lds((const AS1 void*)gb,
                                       (AS3 void*)(Bs + p * 4096 + wave * 1024), 16, 0, 0);
    }
    __syncthreads();
    #pragma unroll
    for (int kk = 0; kk < 2; ++kk) {
      v8s af[2], bfr[4];
      #pragma unroll
      for (int mi = 0; mi < 2; ++mi)
        af[mi] = *(const v8s*)(As + (wm * 32 + mi * 16 + l15) * 128 + (((kk * 4 + l4) ^ l7) << 4));
      #pragma unroll
      for (int ni = 0; ni < 4; ++ni)
        bfr[ni] = *(const v8s*)(Bs + (wn * 64 + ni * 16 + l15) * 128 + (((kk * 4 + l4) ^ l7) << 4));
      #pragma unroll
      for (int mi = 0; mi < 2; ++mi)
        #pragma unroll
        for (int ni = 0; ni < 4; ++ni)
          acc[mi][ni] = __builtin_amdgcn_mfma_f32_16x16x32_bf16(af[mi], bfr[ni], acc[mi][ni], 0, 0, 0);
    }
  }

  if (!F32OUT && n0 >= 1280) {
    // v columns -> Vt[b][g][d][t], 4 contiguous t per lane
    #pragma unroll
    for (int mi = 0; mi < 2; ++mi) {
      #pragma unroll
      for (int ni = 0; ni < 4; ++ni) {
        int col = n0 + wn * 64 + ni * 16 + l15;
        float bv = bias[col];
        int c2 = col - 1280;
        int gg = c2 >> 6, dd = c2 & 63;
        int row = m0 + wm * 32 + mi * 16 + l4 * 4;
        int bb = row >> 11, tt = row & 2047;
        ushort4 ov;
        ov.x = f2bf(acc[mi][ni][0] + bv);
        ov.y = f2bf(acc[mi][ni][1] + bv);
        ov.z = f2bf(acc[mi][ni][2] + bv);
        ov.w = f2bf(acc[mi][ni][3] + bv);
        *(ushort4*)(vtH + ((size_t)((bb * Gn + gg) * 64 + dd)) * Tn + tt) = ov;
      }
    }
  } else if (!F32OUT) {
    // q/k region: fused interleaved RoPE. col parity == lane parity, partner = lane^1.
    #pragma unroll
    for (int mi = 0; mi < 2; ++mi) {
      #pragma unroll
      for (int ni = 0; ni < 4; ++ni) {
        int col = n0 + wn * 64 + ni * 16 + l15;
        float bv = bias[col];
        int d2 = (col & 63) >> 1;
        bool even = !(col & 1);
        #pragma unroll
        for (int r = 0; r < 4; ++r) {
          int row = m0 + wm * 32 + mi * 16 + l4 * 4 + r;
          int tt = row & 2047;
          float2 cs = table[tt * 32 + d2];
          float v = acc[mi][ni][r] + bv;
          float prt = __shfl_xor(v, 1);
          float ov = even ? (v * cs.x - prt * cs.y) : (prt * cs.y + v * cs.x);
          outH[(size_t)row * N + col] = f2bf(ov);
        }
      }
    }
  } else {
    #pragma unroll
    for (int mi = 0; mi < 2; ++mi) {
      #pragma unroll
      for (int ni = 0; ni < 4; ++ni) {
        int col = n0 + wn * 64 + ni * 16 + l15;
        float bv = bias[col];
        #pragma unroll
        for (int r = 0; r < 4; ++r) {
          int row = m0 + wm * 32 + mi * 16 + l4 * 4 + r;
          outF[(size_t)row * N + col] = acc[mi][ni][r] + bv;
        }
      }
    }
  }
}

// ---------------- Flash attention, GQA + sliding window + sink ----------------
// 1D grid of 1024 blocks, 256 thr = 4 waves, QBLK=64: wave w owns rows [qt0+16w, qt0+16w+16).
// 4 blocks/CU (LDS 40KB) for cross-block barrier-drain hiding. Load-balance pairing:
// b=1 half gets reversed q-tile index. KVBLK=64 double-buffered; sink register pre-phase;
// per-wave swizzled LDS P buffer; per-lane lsm partial reduced in epilogue.
__global__ __launch_bounds__(256) void k_attn(const unsigned short* __restrict__ qkv,
                                              const unsigned short* __restrict__ vt,
                                              unsigned short* __restrict__ o) {
  __shared__ char smem[2 * 16384 + 8192];    // 2 bufs (K 8KB | V^T 8KB) + 4 waves x 2KB P
  int id = blockIdx.x;
  int half = id >> 9, r9 = id & 511;
  int h = r9 >> 5;
  int qtile = half ? (31 - (r9 & 31)) : (r9 & 31);
  int b = half;
  int qt0 = qtile * 64;
  int g = h >> 2;
  int t = threadIdx.x, lane = t & 63, wave = t >> 6;
  int l15 = lane & 15, l4 = lane >> 4;
  int l7 = l15 & 7;
  int qw0 = qt0 + wave * 16;
  char* Pb = smem + 32768 + wave * 2048;

  // tile schedule: when qt0 > WIN, sink keys 0-3 handled by register pre-phase
  int jt_end = qtile;
  int wstart = (qt0 > WIN) ? ((qt0 - WIN) >> 6) : 0;
  int nIt = jt_end - wstart + 1;
  bool sinkPre = (wstart > 0);

  const unsigned short* gk0 = qkv + (size_t)(b * Tn) * NQKV + 1024 + g * 64;
  const unsigned short* gv0 = vt + (size_t)((b * Gn + g) * 64) * Tn;

  auto stageKV = [&](int buf, int j0) {
    #pragma unroll
    for (int p = 0; p < 2; ++p) {
      int cid = p * 256 + t;
      int sr = cid >> 3, sc = cid & 7;
      int scs = (sc ^ (sr & 7)) << 3;   // pre-swizzled element offset
      __builtin_amdgcn_global_load_lds(
          (const AS1 void*)(gk0 + (size_t)(j0 + sr) * NQKV + scs),
          (AS3 void*)(smem + buf * 16384 + p * 4096 + wave * 1024), 16, 0, 0);
      __builtin_amdgcn_global_load_lds(
          (const AS1 void*)(gv0 + (size_t)sr * Tn + j0 + scs),
          (AS3 void*)(smem + buf * 16384 + 8192 + p * 4096 + wave * 1024), 16, 0, 0);
    }
  };

  stageKV(0, wstart << 6);

  // Q fragments direct from global (post-RoPE, scale pre-folded)
  v8s Qf[2];
  #pragma unroll
  for (int hf = 0; hf < 2; ++hf)
    Qf[hf] = *(const v8s*)(qkv + (size_t)(b * Tn + qw0 + l15) * NQKV + h * 64 + hf * 32 + l4 * 8);

  float m = -INFINITY, lsm = 0.f;   // lsm per-lane partial; reduced at end
  v4f accO[4] = {};

  if (sinkPre) {
    // ---- sink register pre-phase: keys 0-15 (only 0-3 valid), overlaps first stage ----
    const unsigned short* kr = gk0 + (size_t)l15 * NQKV + l4 * 8;
    v8s kf0 = *(const v8s*)(kr);
    v8s kf1 = *(const v8s*)(kr + 32);
    v4f z = {};
    z = __builtin_amdgcn_mfma_f32_16x16x32_bf16(kf0, Qf[0], z, 0, 0, 0);
    z = __builtin_amdgcn_mfma_f32_16x16x32_bf16(kf1, Qf[1], z, 0, 0, 0);
    float mt = -1e30f;
    float pv4[4];
    #pragma unroll
    for (int r = 0; r < 4; ++r) {
      float sv = (l4 == 0) ? z[r] : -1e30f;   // key = l4*4+r valid iff < 4
      pv4[r] = sv;
      mt = fmaxf(mt, sv);
    }
    mt = fmaxf(mt, __shfl_xor(mt, 16));
    mt = fmaxf(mt, __shfl_xor(mt, 32));
    m = mt;
    float p0 = exp2f(pv4[0] - m), p1 = exp2f(pv4[1] - m);
    float p2 = exp2f(pv4[2] - m), p3 = exp2f(pv4[3] - m);
    lsm = (p0 + p1) + (p2 + p3);
    unsigned long long w = ((unsigned long long)pack_bf2(p3, p2) << 32) | pack_bf2(p1, p0);
    *(unsigned long long*)(Pb + l15 * 128 + ((l4 * 8) ^ (l7 << 4))) = w;
    *(unsigned long long*)(Pb + l15 * 128 + ((32 + l4 * 8) ^ (l7 << 4))) = 0ull;
    asm volatile("s_waitcnt lgkmcnt(0)" ::: "memory");
    __builtin_amdgcn_sched_barrier(0);
    v8s pfrag = *(const v8s*)(Pb + l15 * 128 + ((l4 * 16) ^ (l7 << 4)));
    #pragma unroll
    for (int db = 0; db < 4; ++db) {
      int d = db * 16 + l15;
      v8s vf = *(const v8s*)(gv0 + (size_t)d * Tn + l4 * 8);
      accO[db] = __builtin_amdgcn_mfma_f32_16x16x32_bf16(vf, pfrag, accO[db], 0, 0, 0);
    }
  }

  __syncthreads();

  for (int it = 0; it < nIt; ++it) {
    int cur = it & 1;
    if (it + 1 < nIt) stageKV(cur ^ 1, (wstart + it + 1) << 6);
    int j0 = (wstart + it) << 6;

    bool skip = (j0 > qw0 + 15) || ((j0 + 63 < qw0 - WIN) && (j0 >= SINKN));
    if (!skip) {
      const char* Kb = smem + cur * 16384;
      const char* Vb = Kb + 8192;
      v4f s[4];
      __builtin_amdgcn_s_setprio(1);
      #pragma unroll
      for (int kb = 0; kb < 4; ++kb) {
        int r = kb * 16 + l15;
        v8s kf0 = *(const v8s*)(Kb + r * 128 + ((l4 ^ (r & 7)) << 4));
        v8s kf1 = *(const v8s*)(Kb + r * 128 + (((4 + l4) ^ (r & 7)) << 4));
        v4f z = {};
        z = __builtin_amdgcn_mfma_f32_16x16x32_bf16(kf0, Qf[0], z, 0, 0, 0);
        s[kb] = __builtin_amdgcn_mfma_f32_16x16x32_bf16(kf1, Qf[1], z, 0, 0, 0);
      }
      __builtin_amdgcn_s_setprio(0);
      bool needMask = !((j0 + 63 <= qw0) && (j0 >= qw0 + 15 - WIN));
      if (needMask) {
        #pragma unroll
        for (int kb = 0; kb < 4; ++kb)
          #pragma unroll
          for (int r = 0; r < 4; ++r) {
            int j = j0 + kb * 16 + l4 * 4 + r;
            int qg = qw0 + l15;
            bool valid = (j <= qg) && ((j >= qg - WIN) || (j < SINKN));
            s[kb][r] = valid ? s[kb][r] : -1e30f;
          }
      }
      float mt = -1e30f;
      #pragma unroll
      for (int kb = 0; kb < 4; ++kb)
        #pragma unroll
        for (int r = 0; r < 4; ++r) mt = fmaxf(mt, s[kb][r]);
      mt = fmaxf(mt, __shfl_xor(mt, 16));
      mt = fmaxf(mt, __shfl_xor(mt, 32));
      if (!__all(mt <= m + 8.f)) {      // T13 defer-max
        float mnew = fmaxf(m, mt);
        float alpha = exp2f(m - mnew);  // first tile: exp2(-inf)=0
        lsm *= alpha;
        #pragma unroll
        for (int db = 0; db < 4; ++db) {
          accO[db][0] *= alpha; accO[db][1] *= alpha;
          accO[db][2] *= alpha; accO[db][3] *= alpha;
        }
        m = mnew;
      }
      float lsum = 0.f;
      #pragma unroll
      for (int kb = 0; kb < 4; ++kb) {
        float p0 = exp2f(s[kb][0] - m);
        float p1 = exp2f(s[kb][1] - m);
        float p2 = exp2f(s[kb][2] - m);
        float p3 = exp2f(s[kb][3] - m);
        lsum += (p0 + p1) + (p2 + p3);
        unsigned lo = pack_bf2(p1, p0);
        unsigned hi = pack_bf2(p3, p2);
        unsigned long long w = ((unsigned long long)hi << 32) | lo;
        *(unsigned long long*)(Pb + l15 * 128 + ((kb * 32 + l4 * 8) ^ (l7 << 4))) = w;
      }
      lsm += lsum;
      asm volatile("s_waitcnt lgkmcnt(0)" ::: "memory");
      __builtin_amdgcn_sched_barrier(0);

      __builtin_amdgcn_s_setprio(1);
      #pragma unroll
      for (int kc = 0; kc < 2; ++kc) {
        v8s pfrag = *(const v8s*)(Pb + l15 * 128 + ((kc * 64 + l4 * 16) ^ (l7 << 4)));
        #pragma unroll
        for (int db = 0; db < 4; ++db) {
          int d = db * 16 + l15;
          v8s vf = *(const v8s*)(Vb + d * 128 + (((kc * 4 + l4) ^ (d & 7)) << 4));
          accO[db] = __builtin_amdgcn_mfma_f32_16x16x32_bf16(vf, pfrag, accO[db], 0, 0, 0);
        }
      }
      __builtin_amdgcn_s_setprio(0);
    }
    __syncthreads();
  }

  // epilogue lsum reduce, normalize + write O[t][h*64+d] bf16
  lsm += __shfl_xor(lsm, 16);
  lsm += __shfl_xor(lsm, 32);
  float inv = 1.f / lsm;
  size_t orow = (size_t)(b * Tn + qw0 + l15) * 1024 + h * 64;
  #pragma unroll
  for (int db = 0; db < 4; ++db) {
    int d0 = db * 16 + l4 * 4;
    ushort4 ov;
    ov.x = f2bf(accO[db][0] * inv);
    ov.y = f2bf(accO[db][1] * inv);
    ov.z = f2bf(accO[db][2] * inv);
    ov.w = f2bf(accO[db][3] * inv);
    *(ushort4*)(o + orow + d0) = ov;
  }
}

extern "C" void kernel_launch(void* const* d_in, const int* in_sizes, int n_in,
                              void* d_out, int out_size, void* d_ws, size_t ws_size,
                              hipStream_t stream) {
  const float* x  = (const float*)d_in[0];
  const float* Wq = (const float*)d_in[1];
  const float* bq = (const float*)d_in[2];
  const float* Wk = (const float*)d_in[3];
  const float* bk = (const float*)d_in[4];
  const float* Wv = (const float*)d_in[5];
  const float* bv = (const float*)d_in[6];
  const float* Wo = (const float*)d_in[7];
  const float* bo = (const float*)d_in[8];
  const int*   pos = (const int*)d_in[9];
  float* out = (float*)d_out;

  char* ws = (char*)d_ws;
  unsigned short* xb      = (unsigned short*)(ws);                        // 8388608 B (reused as attno)
  unsigned short* wt_qkv  = (unsigned short*)(ws + 8388608);              // 3145728 B
  unsigned short* wt_o    = (unsigned short*)(ws + 11534336);             // 2097152 B
  float*          bias_q  = (float*)(ws + 13631488);                      // 6144 B
  float2*         table   = (float2*)(ws + 13637632);                     // 524288 B
  unsigned short* qkvb    = (unsigned short*)(ws + 14161920);             // 12582912 B
  unsigned short* vt      = (unsigned short*)(ws + 26744832);             // 2097152 B
  unsigned short* attno   = xb;                                           // reuse (x bf16 dead after GEMM1)

  // weights transpose + rope table + bias + x convert, one launch
  k_transpose_all<<<dim3(32, 32, 6), dim3(32, 8), 0, stream>>>(Wq, Wk, Wv, Wo, wt_qkv, wt_o,
                                                               pos, table, bq, bk, bv, bias_q,
                                                               x, xb);
  // qkv = x @ [Wq|Wk|Wv] + bias; q,k -> RoPE'd bf16 in qkvb, v -> vt transposed
  k_gemm_bt<false><<<dim3(12, 64), 256, 0, stream>>>(xb, wt_qkv, bias_q, table, nullptr, qkvb, vt,
                                                     4096, NQKV, 1024);
  // attention (load-balanced 1D grid, 4 blocks/CU)
  k_attn<<<1024, 256, 0, stream>>>(qkvb, vt, attno);
  // out = attn @ Wo + bo  (f32 out)
  k_gemm_bt<true><<<dim3(8, 64), 256, 0, stream>>>(attno, wt_o, bo, nullptr, out, nullptr, nullptr,
                                                   4096, 1024, 1024);
}

// Round 11
// 77.272 us; speedup vs baseline: 1.0379x; 1.0166x over previous
//
#include <hip/hip_runtime.h>
#include <stdint.h>
#include <math.h>

typedef short v8s __attribute__((ext_vector_type(8)));
typedef float v4f __attribute__((ext_vector_type(4)));

#define DEVI static __device__ __forceinline__
#define AS1 __attribute__((address_space(1)))
#define AS3 __attribute__((address_space(3)))

static constexpr int Bn = 2;
static constexpr int Tn = 2048;
static constexpr int Hn = 16;
static constexpr int Gn = 4;
static constexpr int NQKV = 1536;   // H*D + 2*G*D
static constexpr int WIN = 512;
static constexpr int SINKN = 4;
#define SCALE_L2E (0.125f * 1.4426950408889634f)   // D^-0.5 * log2(e), folded into Wq/bq

DEVI unsigned short f2bf(float f) {
  unsigned u = __float_as_uint(f);
  u += 0x7fffu + ((u >> 16) & 1u);
  return (unsigned short)(u >> 16);
}
DEVI float bf2f(unsigned short h) { return __uint_as_float(((unsigned)h) << 16); }
// pack two f32 -> bf16x2 by truncation: low short = lo, high short = hi
DEVI unsigned pack_bf2(float hi, float lo) {
  return __builtin_amdgcn_perm(__float_as_uint(hi), __float_as_uint(lo), 0x07060302u);
}

// ------------- weights transpose + rope table + bias + x-convert, one launch -------------
// z: 0=Wq(scale) 1=Wk 2=Wv 3=Wo 4=rope-table+bias-concat 5=x fp32->bf16
__global__ __launch_bounds__(256) void k_transpose_all(const float* __restrict__ Wq,
                                                       const float* __restrict__ Wk,
                                                       const float* __restrict__ Wv,
                                                       const float* __restrict__ Wo,
                                                       unsigned short* __restrict__ wt_qkv,
                                                       unsigned short* __restrict__ wt_o,
                                                       const int* __restrict__ posp,
                                                       float2* __restrict__ table,
                                                       const float* __restrict__ bq,
                                                       const float* __restrict__ bk,
                                                       const float* __restrict__ bv,
                                                       float* __restrict__ biasout,
                                                       const float* __restrict__ x,
                                                       unsigned short* __restrict__ xb) {
  int z = blockIdx.z;
  int tx = threadIdx.x, ty = threadIdx.y;   // block (32,8)
  if (z == 5) {
    // x -> bf16, 4 float4 per thread (1024 blocks * 256 thr * 4 = 1,048,576 float4)
    int base = (blockIdx.y * 32 + blockIdx.x) * 256 + ty * 32 + tx;
    #pragma unroll
    for (int j = 0; j < 4; ++j) {
      int i = base + j * 262144;
      float4 v = ((const float4*)x)[i];
      ushort4 o;
      o.x = f2bf(v.x); o.y = f2bf(v.y); o.z = f2bf(v.z); o.w = f2bf(v.w);
      ((ushort4*)xb)[i] = o;
    }
    return;
  }
  if (z == 4) {
    int i = (blockIdx.y * 32 + blockIdx.x) * 256 + ty * 32 + tx;
    if (i < Tn * 32) {
      int t = i >> 5, d2 = i & 31;
      float inv = powf(10000.f, -(float)d2 / 32.f);
      float theta = (float)(posp[0] + t) * inv;
      float s, c;
      sincosf(theta, &s, &c);
      table[i] = make_float2(c, s);
    }
    if (i < NQKV)
      biasout[i] = (i < 1024) ? bq[i] * SCALE_L2E : (i < 1280 ? bk[i - 1024] : bv[i - 1280]);
    return;
  }
  const float* W; unsigned short* Wt; int N; float scale = 1.f;
  if (z == 0)      { W = Wq; Wt = wt_qkv;                 N = 1024; scale = SCALE_L2E; }
  else if (z == 1) { W = Wk; Wt = wt_qkv + 1024 * 1024;   N = 256; }
  else if (z == 2) { W = Wv; Wt = wt_qkv + 1280 * 1024;   N = 256; }
  else             { W = Wo; Wt = wt_o;                   N = 1024; }
  int n0 = blockIdx.x * 32, k0 = blockIdx.y * 32;
  if (n0 >= N) return;
  __shared__ float tile[32][33];
  #pragma unroll
  for (int yy = 0; yy < 4; ++yy)
    tile[ty + yy * 8][tx] = W[(size_t)(k0 + ty + yy * 8) * N + n0 + tx];
  __syncthreads();
  #pragma unroll
  for (int yy = 0; yy < 4; ++yy)
    Wt[(size_t)(n0 + ty + yy * 8) * 1024 + k0 + tx] = f2bf(tile[tx][ty + yy * 8] * scale);
}

// ---------------- GEMM: C[M][N] = A[M][K](bf16) * Bt[N][K]^T + bias ----------------
// 64x128 tile, BK=64, 4 waves (2 wm x 2 wn), single-buffer 2-barrier per K-step.
// LDS tiles XOR-swizzled (16B chunk ^= row&7) via pre-swizzled global source (T2/rule21).
// XCD-aware tile swizzle (nwg % 8 == 0 required).  [R8-proven config]
template <bool F32OUT>
__global__ __launch_bounds__(256) void k_gemm_bt(const unsigned short* __restrict__ A,
                                                 const unsigned short* __restrict__ Bt,
                                                 const float* __restrict__ bias,
                                                 const float2* __restrict__ table,
                                                 float* __restrict__ outF,
                                                 unsigned short* __restrict__ outH,
                                                 unsigned short* __restrict__ vtH,
                                                 int M, int N, int K) {
  __shared__ char As[8192];     // [64 rows][128 B] (64 bf16)
  __shared__ char Bs[16384];    // [128 rows][128 B]
  int nx = gridDim.x;
  int nwg = nx * gridDim.y;
  int id = blockIdx.y * nx + blockIdx.x;
  int swz = (id & 7) * (nwg >> 3) + (id >> 3);
  int m0 = (swz / nx) * 64, n0 = (swz % nx) * 128;

  int t = threadIdx.x, lane = t & 63, wave = t >> 6;
  int wm = wave >> 1, wn = wave & 1;
  int l15 = lane & 15, l4 = lane >> 4;
  int l7 = l15 & 7;
  v4f acc[2][4] = {};

  for (int k0 = 0; k0 < K; k0 += 64) {
    __syncthreads();
    #pragma unroll
    for (int p = 0; p < 2; ++p) {     // A: 512 chunks of 16B
      int cid = p * 256 + t;
      int row = cid >> 3, cc = cid & 7;
      const unsigned short* ga = A + (size_t)(m0 + row) * K + k0 + (cc ^ (row & 7)) * 8;
      __builtin_amdgcn_global_load_lds((const AS1 void*)ga,
                                       (AS3 void*)(As + p * 4096 + wave * 1024), 16, 0, 0);
    }
    #pragma unroll
    for (int p = 0; p < 4; ++p) {     // B: 1024 chunks of 16B
      int cid = p * 256 + t;
      int row = cid >> 3, cc = cid & 7;
      const unsigned short* gb = Bt + (size_t)(n0 + row) * K + k0 + (cc ^ (row & 7)) * 8;
      __builtin_amdgcn_global_load_lds((const AS1 void*)gb,
                                       (AS3 void*)(Bs + p * 4096 + wave * 1024), 16, 0, 0);
    }
    __syncthreads();
    #pragma unroll
    for (int kk = 0; kk < 2; ++kk) {
      v8s af[2], bfr[4];
      #pragma unroll
      for (int mi = 0; mi < 2; ++mi)
        af[mi] = *(const v8s*)(As + (wm * 32 + mi * 16 + l15) * 128 + (((kk * 4 + l4) ^ l7) << 4));
      #pragma unroll
      for (int ni = 0; ni < 4; ++ni)
        bfr[ni] = *(const v8s*)(Bs + (wn * 64 + ni * 16 + l15) * 128 + (((kk * 4 + l4) ^ l7) << 4));
      #pragma unroll
      for (int mi = 0; mi < 2; ++mi)
        #pragma unroll
        for (int ni = 0; ni < 4; ++ni)
          acc[mi][ni] = __builtin_amdgcn_mfma_f32_16x16x32_bf16(af[mi], bfr[ni], acc[mi][ni], 0, 0, 0);
    }
  }

  if (!F32OUT && n0 >= 1280) {
    // v columns -> Vt[b][g][d][t], 4 contiguous t per lane
    #pragma unroll
    for (int mi = 0; mi < 2; ++mi) {
      #pragma unroll
      for (int ni = 0; ni < 4; ++ni) {
        int col = n0 + wn * 64 + ni * 16 + l15;
        float bv = bias[col];
        int c2 = col - 1280;
        int gg = c2 >> 6, dd = c2 & 63;
        int row = m0 + wm * 32 + mi * 16 + l4 * 4;
        int bb = row >> 11, tt = row & 2047;
        ushort4 ov;
        ov.x = f2bf(acc[mi][ni][0] + bv);
        ov.y = f2bf(acc[mi][ni][1] + bv);
        ov.z = f2bf(acc[mi][ni][2] + bv);
        ov.w = f2bf(acc[mi][ni][3] + bv);
        *(ushort4*)(vtH + ((size_t)((bb * Gn + gg) * 64 + dd)) * Tn + tt) = ov;
      }
    }
  } else if (!F32OUT) {
    // q/k region: fused interleaved RoPE. col parity == lane parity, partner = lane^1.
    #pragma unroll
    for (int mi = 0; mi < 2; ++mi) {
      #pragma unroll
      for (int ni = 0; ni < 4; ++ni) {
        int col = n0 + wn * 64 + ni * 16 + l15;
        float bv = bias[col];
        int d2 = (col & 63) >> 1;
        bool even = !(col & 1);
        #pragma unroll
        for (int r = 0; r < 4; ++r) {
          int row = m0 + wm * 32 + mi * 16 + l4 * 4 + r;
          int tt = row & 2047;
          float2 cs = table[tt * 32 + d2];
          float v = acc[mi][ni][r] + bv;
          float prt = __shfl_xor(v, 1);
          float ov = even ? (v * cs.x - prt * cs.y) : (prt * cs.y + v * cs.x);
          outH[(size_t)row * N + col] = f2bf(ov);
        }
      }
    }
  } else {
    #pragma unroll
    for (int mi = 0; mi < 2; ++mi) {
      #pragma unroll
      for (int ni = 0; ni < 4; ++ni) {
        int col = n0 + wn * 64 + ni * 16 + l15;
        float bv = bias[col];
        #pragma unroll
        for (int r = 0; r < 4; ++r) {
          int row = m0 + wm * 32 + mi * 16 + l4 * 4 + r;
          outF[(size_t)row * N + col] = acc[mi][ni][r] + bv;
        }
      }
    }
  }
}

// ---------------- Flash attention, GQA + sliding window + sink (R8 structure) ----------------
// 1D grid of 512 blocks, 512 thr = 8 waves, wave w owns q rows [qt0+16w, qt0+16w+16).
// KVBLK=64. Sink register pre-phase when qt0 > WIN. Swapped QK^T; K and V^T double-buffered.
// P redistribution via per-wave swizzled LDS buffer; per-lane lsm partial reduced in epilogue.
__global__ __launch_bounds__(512) void k_attn(const unsigned short* __restrict__ qkv,
                                              const unsigned short* __restrict__ vt,
                                              unsigned short* __restrict__ o) {
  __shared__ char smem[2 * 16384 + 16384];    // 2 bufs (K 8KB | V^T 8KB) + 8 waves x 2KB P
  int id = blockIdx.x;
  int half = id >> 8, r5 = id & 255;
  int h = r5 >> 4;
  int qtile = half ? (15 - (r5 & 15)) : (r5 & 15);
  int b = half;
  int qt0 = qtile * 128;
  int g = h >> 2;
  int t = threadIdx.x, lane = t & 63, wave = t >> 6;
  int l15 = lane & 15, l4 = lane >> 4;
  int l7 = l15 & 7;
  int qw0 = qt0 + wave * 16;
  char* Pb = smem + 32768 + wave * 2048;

  int jt_end = (qt0 + 127) >> 6;
  int wstart = (qt0 > WIN) ? ((qt0 - WIN) >> 6) : 0;
  int nIt = jt_end - wstart + 1;
  bool sinkPre = (wstart > 0);

  const unsigned short* gk0 = qkv + (size_t)(b * Tn) * NQKV + 1024 + g * 64;
  const unsigned short* gv0 = vt + (size_t)((b * Gn + g) * 64) * Tn;

  int sr = t >> 3, sc = t & 7;
  int scs = (sc ^ (sr & 7)) << 3;
  const unsigned short* gkb = gk0 + (size_t)sr * NQKV + scs;
  const unsigned short* gvb = gv0 + (size_t)sr * Tn + scs;

  auto stageKV = [&](int buf, int j0) {
    __builtin_amdgcn_global_load_lds((const AS1 void*)(gkb + (size_t)j0 * NQKV),
                                     (AS3 void*)(smem + buf * 16384 + wave * 1024), 16, 0, 0);
    __builtin_amdgcn_global_load_lds((const AS1 void*)(gvb + j0),
                                     (AS3 void*)(smem + buf * 16384 + 8192 + wave * 1024), 16, 0, 0);
  };

  stageKV(0, wstart << 6);

  v8s Qf[2];
  #pragma unroll
  for (int hf = 0; hf < 2; ++hf)
    Qf[hf] = *(const v8s*)(qkv + (size_t)(b * Tn + qw0 + l15) * NQKV + h * 64 + hf * 32 + l4 * 8);

  float m = -INFINITY, lsm = 0.f;   // lsm per-lane partial; reduced at end
  v4f accO[4] = {};

  if (sinkPre) {
    const unsigned short* kr = gk0 + (size_t)l15 * NQKV + l4 * 8;
    v8s kf0 = *(const v8s*)(kr);
    v8s kf1 = *(const v8s*)(kr + 32);
    v4f z = {};
    z = __builtin_amdgcn_mfma_f32_16x16x32_bf16(kf0, Qf[0], z, 0, 0, 0);
    z = __builtin_amdgcn_mfma_f32_16x16x32_bf16(kf1, Qf[1], z, 0, 0, 0);
    float mt = -1e30f;
    float pv4[4];
    #pragma unroll
    for (int r = 0; r < 4; ++r) {
      float sv = (l4 == 0) ? z[r] : -1e30f;
      pv4[r] = sv;
      mt = fmaxf(mt, sv);
    }
    mt = fmaxf(mt, __shfl_xor(mt, 16));
    mt = fmaxf(mt, __shfl_xor(mt, 32));
    m = mt;
    float p0 = exp2f(pv4[0] - m), p1 = exp2f(pv4[1] - m);
    float p2 = exp2f(pv4[2] - m), p3 = exp2f(pv4[3] - m);
    lsm = (p0 + p1) + (p2 + p3);
    unsigned long long w = ((unsigned long long)pack_bf2(p3, p2) << 32) | pack_bf2(p1, p0);
    *(unsigned long long*)(Pb + l15 * 128 + ((l4 * 8) ^ (l7 << 4))) = w;
    *(unsigned long long*)(Pb + l15 * 128 + ((32 + l4 * 8) ^ (l7 << 4))) = 0ull;
    asm volatile("s_waitcnt lgkmcnt(0)" ::: "memory");
    __builtin_amdgcn_sched_barrier(0);
    v8s pfrag = *(const v8s*)(Pb + l15 * 128 + ((l4 * 16) ^ (l7 << 4)));
    #pragma unroll
    for (int db = 0; db < 4; ++db) {
      int d = db * 16 + l15;
      v8s vf = *(const v8s*)(gv0 + (size_t)d * Tn + l4 * 8);
      accO[db] = __builtin_amdgcn_mfma_f32_16x16x32_bf16(vf, pfrag, accO[db], 0, 0, 0);
    }
  }

  __syncthreads();

  for (int it = 0; it < nIt; ++it) {
    int cur = it & 1;
    if (it + 1 < nIt) stageKV(cur ^ 1, (wstart + it + 1) << 6);
    int j0 = (wstart + it) << 6;

    bool skip = (j0 > qw0 + 15) || ((j0 + 63 < qw0 - WIN) && (j0 >= SINKN));
    if (!skip) {
      const char* Kb = smem + cur * 16384;
      const char* Vb = Kb + 8192;
      v4f s[4];
      __builtin_amdgcn_s_setprio(1);
      #pragma unroll
      for (int kb = 0; kb < 4; ++kb) {
        int r = kb * 16 + l15;
        v8s kf0 = *(const v8s*)(Kb + r * 128 + ((l4 ^ (r & 7)) << 4));
        v8s kf1 = *(const v8s*)(Kb + r * 128 + (((4 + l4) ^ (r & 7)) << 4));
        v4f z = {};
        z = __builtin_amdgcn_mfma_f32_16x16x32_bf16(kf0, Qf[0], z, 0, 0, 0);
        s[kb] = __builtin_amdgcn_mfma_f32_16x16x32_bf16(kf1, Qf[1], z, 0, 0, 0);
      }
      __builtin_amdgcn_s_setprio(0);
      bool needMask = !((j0 + 63 <= qw0) && (j0 >= qw0 + 15 - WIN));
      if (needMask) {
        #pragma unroll
        for (int kb = 0; kb < 4; ++kb)
          #pragma unroll
          for (int r = 0; r < 4; ++r) {
            int j = j0 + kb * 16 + l4 * 4 + r;
            int qg = qw0 + l15;
            bool valid = (j <= qg) && ((j >= qg - WIN) || (j < SINKN));
            s[kb][r] = valid ? s[kb][r] : -1e30f;
          }
      }
      float mt = -1e30f;
      #pragma unroll
      for (int kb = 0; kb < 4; ++kb)
        #pragma unroll
        for (int r = 0; r < 4; ++r) mt = fmaxf(mt, s[kb][r]);
      mt = fmaxf(mt, __shfl_xor(mt, 16));
      mt = fmaxf(mt, __shfl_xor(mt, 32));
      if (!__all(mt <= m + 8.f)) {      // T13 defer-max
        float mnew = fmaxf(m, mt);
        float alpha = exp2f(m - mnew);
        lsm *= alpha;
        #pragma unroll
        for (int db = 0; db < 4; ++db) {
          accO[db][0] *= alpha; accO[db][1] *= alpha;
          accO[db][2] *= alpha; accO[db][3] *= alpha;
        }
        m = mnew;
      }
      float lsum = 0.f;
      #pragma unroll
      for (int kb = 0; kb < 4; ++kb) {
        float p0 = exp2f(s[kb][0] - m);
        float p1 = exp2f(s[kb][1] - m);
        float p2 = exp2f(s[kb][2] - m);
        float p3 = exp2f(s[kb][3] - m);
        lsum += (p0 + p1) + (p2 + p3);
        unsigned lo = pack_bf2(p1, p0);
        unsigned hi = pack_bf2(p3, p2);
        unsigned long long w = ((unsigned long long)hi << 32) | lo;
        *(unsigned long long*)(Pb + l15 * 128 + ((kb * 32 + l4 * 8) ^ (l7 << 4))) = w;
      }
      lsm += lsum;
      asm volatile("s_waitcnt lgkmcnt(0)" ::: "memory");
      __builtin_amdgcn_sched_barrier(0);

      __builtin_amdgcn_s_setprio(1);
      #pragma unroll
      for (int kc = 0; kc < 2; ++kc) {
        v8s pfrag = *(const v8s*)(Pb + l15 * 128 + ((kc * 64 + l4 * 16) ^ (l7 << 4)));
        #pragma unroll
        for (int db = 0; db < 4; ++db) {
          int d = db * 16 + l15;
          v8s vf = *(const v8s*)(Vb + d * 128 + (((kc * 4 + l4) ^ (d & 7)) << 4));
          accO[db] = __builtin_amdgcn_mfma_f32_16x16x32_bf16(vf, pfrag, accO[db], 0, 0, 0);
        }
      }
      __builtin_amdgcn_s_setprio(0);
    }
    __syncthreads();
  }

  lsm += __shfl_xor(lsm, 16);
  lsm += __shfl_xor(lsm, 32);
  float inv = 1.f / lsm;
  size_t orow = (size_t)(b * Tn + qw0 + l15) * 1024 + h * 64;
  #pragma unroll
  for (int db = 0; db < 4; ++db) {
    int d0 = db * 16 + l4 * 4;
    ushort4 ov;
    ov.x = f2bf(accO[db][0] * inv);
    ov.y = f2bf(accO[db][1] * inv);
    ov.z = f2bf(accO[db][2] * inv);
    ov.w = f2bf(accO[db][3] * inv);
    *(ushort4*)(o + orow + d0) = ov;
  }
}

extern "C" void kernel_launch(void* const* d_in, const int* in_sizes, int n_in,
                              void* d_out, int out_size, void* d_ws, size_t ws_size,
                              hipStream_t stream) {
  const float* x  = (const float*)d_in[0];
  const float* Wq = (const float*)d_in[1];
  const float* bq = (const float*)d_in[2];
  const float* Wk = (const float*)d_in[3];
  const float* bk = (const float*)d_in[4];
  const float* Wv = (const float*)d_in[5];
  const float* bv = (const float*)d_in[6];
  const float* Wo = (const float*)d_in[7];
  const float* bo = (const float*)d_in[8];
  const int*   pos = (const int*)d_in[9];
  float* out = (float*)d_out;

  char* ws = (char*)d_ws;
  unsigned short* xb      = (unsigned short*)(ws);                        // 8388608 B (reused as attno)
  unsigned short* wt_qkv  = (unsigned short*)(ws + 8388608);              // 3145728 B
  unsigned short* wt_o    = (unsigned short*)(ws + 11534336);             // 2097152 B
  float*          bias_q  = (float*)(ws + 13631488);                      // 6144 B
  float2*         table   = (float2*)(ws + 13637632);                     // 524288 B
  unsigned short* qkvb    = (unsigned short*)(ws + 14161920);             // 12582912 B
  unsigned short* vt      = (unsigned short*)(ws + 26744832);             // 2097152 B
  unsigned short* attno   = xb;                                           // reuse (x bf16 dead after GEMM1)

  // weights transpose + rope table + bias + x convert, one launch
  k_transpose_all<<<dim3(32, 32, 6), dim3(32, 8), 0, stream>>>(Wq, Wk, Wv, Wo, wt_qkv, wt_o,
                                                               pos, table, bq, bk, bv, bias_q,
                                                               x, xb);
  // qkv = x @ [Wq|Wk|Wv] + bias; q,k -> RoPE'd bf16 in qkvb, v -> vt transposed
  k_gemm_bt<false><<<dim3(12, 64), 256, 0, stream>>>(xb, wt_qkv, bias_q, table, nullptr, qkvb, vt,
                                                     4096, NQKV, 1024);
  // attention (load-balanced 1D grid)
  k_attn<<<512, 512, 0, stream>>>(qkvb, vt, attno);
  // out = attn @ Wo + bo  (f32 out)
  k_gemm_bt<true><<<dim3(8, 64), 256, 0, stream>>>(attno, wt_o, bo, nullptr, out, nullptr, nullptr,
                                                   4096, 1024, 1024);
}